// Round 3
// baseline (176.343 us; speedup 1.0000x reference)
//
#include <hip/hip_runtime.h>

// GeodesicAttention: B=4, T=2048, D=1024, R=32
//   y = x @ U; p[t,j] = exp(2 y_t.y_j - n_j - n_t) in (0,1], NO online max.
// Round 9 = round 8 with the two non-algorithmic risks removed:
//   - Bs single-buffered [128x128] (33,280 B total LDS — same footprint the
//     verified round-1 kernel launched with; round 8's 66,048 B dbuf is the
//     prime suspect for a silent launch failure -> memset-zero output).
//   - exp2 via __builtin_amdgcn_exp2f (round-1-verified), not raw inline asm
//     (TRANS-op hazard recognizer can't see into asm blocks).
// Schedule per 128-j tile: barrier (prev PV done) -> issue global_load_lds ->
// scores fully in registers (covers the loads) -> barrier (vmcnt drain +
// visibility) -> PV. Race-free unconditionally.
//   - Permuted-row score MFMA: aj frag row i <- global j = g(ja,i) =
//     32(ja>>1)+8(i>>2)+(ja&1)*4+(i&3), so the score C-fragment IS the PV
//     A-fragment (lane m,quad holds P[t=m][j=8*quad+e]). P never touches LDS.
//   - prep: 128t x 128d blocks, coalesced f32x4 loads, U-transpose in-LDS,
//     256B-chunk xt stores, ypart stored [slab][b][r][t] contiguously.
//   - reduce: LDS transpose, coalesced in+out; ybf scaled by sqrt(2/ln2) so
//     score = log2(p) directly (exp2, no extra mul).
#define B_ 4
#define T_ 2048
#define D_ 1024
#define R_ 32
#define XP 136   // LDS pad stride in shorts for 128-wide bf16 tiles

typedef __attribute__((ext_vector_type(8))) short short8;
typedef __attribute__((ext_vector_type(4))) float f32x4;
typedef __attribute__((ext_vector_type(4))) unsigned short us4;
typedef __attribute__((ext_vector_type(8))) unsigned short us8;

__device__ __forceinline__ unsigned short f2bf(float f) {
  union { float f; unsigned u; } v; v.f = f;
  unsigned r = (v.u + 0x7fffu + ((v.u >> 16) & 1u)) >> 16;
  return (unsigned short)r;
}
__device__ __forceinline__ float bf2f(unsigned short h) {
  union { unsigned u; float f; } v; v.u = (unsigned)h << 16;
  return v.f;
}

// ---------------- prep: xt + Ut (in-LDS) + partial y ------------------------
// Block = 128 t x 128 d. grid (T/128, B, D/128).
__global__ __launch_bounds__(256)
void geo_prep(const float* __restrict__ x, const float* __restrict__ U,
              unsigned short* __restrict__ xt, float* __restrict__ ypart) {
  __shared__ unsigned short xs[128 * XP];   // bf16 x tile [t][d]
  __shared__ unsigned short uts[32 * XP];   // bf16 U^T slab [r][d]
  const int bb = blockIdx.y, t0 = blockIdx.x * 128, d0 = blockIdx.z * 128;
  const int tid = threadIdx.x, w = tid >> 6, lane = tid & 63;
  const int m = lane & 15, quad = lane >> 4;

  // U slab [d0..d0+128][32] : 4 coalesced f32x4 per thread
  f32x4 uv[4];
  #pragma unroll
  for (int p = 0; p < 4; p++) {
    const int i4 = p * 256 + tid;            // (du = i4>>3, ru4 = i4&7)
    uv[p] = *(const f32x4*)(U + (size_t)(d0 + (i4 >> 3)) * R_ + (i4 & 7) * 4);
  }
  // x tile [t0..+128][d0..+128] : 16 coalesced f32x4 per thread
  f32x4 xv[16];
  #pragma unroll
  for (int p = 0; p < 16; p++) {
    const int i4 = p * 256 + tid;            // (r = i4>>5, c4 = i4&31)
    xv[p] = *(const f32x4*)(x + ((size_t)bb * T_ + t0 + (i4 >> 5)) * D_ + d0 + (i4 & 31) * 4);
  }
  // U transpose into LDS: uts[r][du] = bf16(U[du][r])
  #pragma unroll
  for (int p = 0; p < 4; p++) {
    const int i4 = p * 256 + tid; const int du = i4 >> 3, ru4 = i4 & 7;
    #pragma unroll
    for (int k = 0; k < 4; k++) uts[(ru4 * 4 + k) * XP + du] = f2bf(uv[p][k]);
  }
  // x -> bf16 LDS
  #pragma unroll
  for (int p = 0; p < 16; p++) {
    const int i4 = p * 256 + tid; const int r = i4 >> 5, c4 = i4 & 31;
    us4 c;
    c[0] = f2bf(xv[p][0]); c[1] = f2bf(xv[p][1]);
    c[2] = f2bf(xv[p][2]); c[3] = f2bf(xv[p][3]);
    *(us4*)&xs[r * XP + c4 * 4] = c;
  }
  __syncthreads();
  // xt transposed store: thread (d = tid>>1, th = tid&1) -> 256B chunks
  {
    const int d = tid >> 1, th = tid & 1;
    unsigned short* xo = xt + ((size_t)bb * D_ + d0 + d) * T_ + t0 + th * 64;
    #pragma unroll
    for (int i = 0; i < 8; i++) {
      us8 o;
      #pragma unroll
      for (int k = 0; k < 8; k++) o[k] = xs[(th * 64 + i * 8 + k) * XP + d];
      *(us8*)(xo + i * 8) = o;
    }
  }
  // partial y: A = x rows (t, 32/wave), B = uts rows (r), K = 128
  f32x4 acc[2][2];
  #pragma unroll
  for (int i = 0; i < 2; i++)
    #pragma unroll
    for (int j = 0; j < 2; j++) acc[i][j] = (f32x4){0.f, 0.f, 0.f, 0.f};
  #pragma unroll
  for (int ks = 0; ks < 4; ks++) {
    const int ko = ks * 32 + quad * 8;
    short8 a0 = *(const short8*)&xs[(w * 32 + m) * XP + ko];
    short8 a1 = *(const short8*)&xs[(w * 32 + 16 + m) * XP + ko];
    short8 b0 = *(const short8*)&uts[m * XP + ko];
    short8 b1 = *(const short8*)&uts[(16 + m) * XP + ko];
    acc[0][0] = __builtin_amdgcn_mfma_f32_16x16x32_bf16(a0, b0, acc[0][0], 0, 0, 0);
    acc[0][1] = __builtin_amdgcn_mfma_f32_16x16x32_bf16(a0, b1, acc[0][1], 0, 0, 0);
    acc[1][0] = __builtin_amdgcn_mfma_f32_16x16x32_bf16(a1, b0, acc[1][0], 0, 0, 0);
    acc[1][1] = __builtin_amdgcn_mfma_f32_16x16x32_bf16(a1, b1, acc[1][1], 0, 0, 0);
  }
  // ypart layout [slab][b][r][t]: C rows (t) are reg-consecutive -> f32x4 stores
  #pragma unroll
  for (int tb = 0; tb < 2; tb++)
    #pragma unroll
    for (int nb = 0; nb < 2; nb++)
      *(f32x4*)(ypart + ((size_t)(blockIdx.z * B_ + bb) * R_ + nb * 16 + m) * T_
                + t0 + w * 32 + tb * 16 + quad * 4) = acc[tb][nb];
}

// ---------------- reduce: y = sum_s ypart; ybf (exp2-scaled), nsq -----------
// Block = 128 t. grid (T/128, B). SCALE = sqrt(2/ln2).
__global__ __launch_bounds__(256)
void geo_reduce(const float* __restrict__ ypart, unsigned short* __restrict__ ybf,
                float* __restrict__ nsq) {
  __shared__ float ls[32 * 132];
  const int t0 = blockIdx.x * 128, bb = blockIdx.y;
  const int tid = threadIdx.x;
  f32x4 vs[4];
  #pragma unroll
  for (int p = 0; p < 4; p++) vs[p] = (f32x4){0.f, 0.f, 0.f, 0.f};
  for (int s = 0; s < 8; s++) {
    #pragma unroll
    for (int p = 0; p < 4; p++) {
      const int i4 = p * 256 + tid;          // (r = i4>>5, c4 = i4&31)
      f32x4 v = *(const f32x4*)(ypart + ((size_t)(s * B_ + bb) * R_ + (i4 >> 5)) * T_
                                + t0 + (i4 & 31) * 4);
      #pragma unroll
      for (int k = 0; k < 4; k++) vs[p][k] += v[k];
    }
  }
  #pragma unroll
  for (int p = 0; p < 4; p++) {
    const int i4 = p * 256 + tid;
    *(f32x4*)&ls[(i4 >> 5) * 132 + (i4 & 31) * 4] = vs[p];
  }
  __syncthreads();
  const int t = tid >> 1, rh = tid & 1;
  us8 o0, o1; float part = 0.f;
  #pragma unroll
  for (int k = 0; k < 8; k++) {
    const unsigned short h = f2bf(1.69864446f * ls[(rh * 16 + k) * 132 + t]);
    const float bv = bf2f(h); part += bv * bv; o0[k] = h;
  }
  #pragma unroll
  for (int k = 0; k < 8; k++) {
    const unsigned short h = f2bf(1.69864446f * ls[(rh * 16 + 8 + k) * 132 + t]);
    const float bv = bf2f(h); part += bv * bv; o1[k] = h;
  }
  part += __shfl_xor(part, 1, 64);
  unsigned short* yo = ybf + ((size_t)bb * T_ + t0 + t) * R_ + rh * 16;
  *(us8*)yo = o0;
  *(us8*)(yo + 8) = o1;
  if (rh == 0) nsq[bb * T_ + t0 + t] = 0.5f * part;
}

// ---------------- fused: out[t, d-slab] = (exp2-P @ xt^T) / rowsum ----------
// Block = (t-tile 128) x (d-slab 128); wave w owns out rows [w*32, w*32+32).
// P stays in registers (permuted-row score MFMA == PV A-fragment layout).
__global__ __launch_bounds__(256, 2)
void geo_fused(const unsigned short* __restrict__ ybf,
               const float* __restrict__ nsq,
               const unsigned short* __restrict__ xt,
               float* __restrict__ out) {
  __shared__ unsigned short Bs[128 * 128];   // xt tile, XOR-swizzled (32 KB)
  __shared__ float l_s[128];
  const int bz = blockIdx.z, id = blockIdx.x;
  const int d0 = (id & 7) * 128;   // id%8 -> d-slab: each XCD reuses one xt panel
  const int t0 = (id >> 3) * 128;
  const int tid = threadIdx.x, w = tid >> 6, lane = tid & 63;
  const int m = lane & 15, quad = lane >> 4;
  const int srow4 = lane >> 4, blk = lane & 15;

  const unsigned short* yb = ybf + (size_t)bz * T_ * R_;
  const float* nq = nsq + bz * T_;
  const unsigned short* Xb = xt + ((size_t)bz * D_ + d0) * T_;

#define STAGE(J0) do {                                                           \
    _Pragma("unroll")                                                            \
    for (int cc = 0; cc < 8; cc++) {                                             \
      const int rbase = w * 32 + cc * 4;                                         \
      const int row = rbase + srow4;                                             \
      const int sw = (blk ^ (row & 7)) * 8;                                      \
      __builtin_amdgcn_global_load_lds(                                          \
        (const __attribute__((address_space(1))) void*)(Xb + (size_t)row * T_ + (J0) + sw), \
        (__attribute__((address_space(3))) void*)(Bs + rbase * 128), 16, 0, 0);  \
    } } while (0)

  // hoisted t-side fragments
  short8 at[2]; float nnt[2]; float lsum[2] = {0.f, 0.f};
  #pragma unroll
  for (int tb = 0; tb < 2; tb++) {
    at[tb] = *(const short8*)(yb + (size_t)(t0 + w * 32 + tb * 16 + m) * R_ + quad * 8);
    nnt[tb] = -nq[t0 + w * 32 + tb * 16 + m];
  }

  f32x4 acc[2][8];
  #pragma unroll
  for (int i = 0; i < 2; i++)
    #pragma unroll
    for (int j = 0; j < 8; j++) acc[i][j] = (f32x4){0.f, 0.f, 0.f, 0.f};

  for (int it = 0; it < 16; ++it) {
    const int j0 = it * 128;
    __syncthreads();               // all waves done reading Bs (prev PV)
    STAGE(j0);                     // issue loads; scores below cover them
    // j-side fragments, PERMUTED rows: frag-row i <- global j = g(ja,i)
    short8 aj[8]; f32x4 njv[8];
    #pragma unroll
    for (int ja = 0; ja < 8; ja++) {
      const int jr = 32 * (ja >> 1) + 8 * (m >> 2) + (ja & 1) * 4 + (m & 3);
      aj[ja] = *(const short8*)(yb + (size_t)(j0 + jr) * R_ + quad * 8);
      njv[ja] = *(const f32x4*)(nq + j0 + 32 * (ja >> 1) + (ja & 1) * 4 + 8 * quad);
    }
    // scores -> exp2 -> bf16 PV A-frags, fully in registers
    short8 pfrag[2][4];
    #pragma unroll
    for (int tb = 0; tb < 2; tb++) {
      #pragma unroll
      for (int ja = 0; ja < 8; ja++) {
        f32x4 cin;
        #pragma unroll
        for (int r = 0; r < 4; r++) cin[r] = nnt[tb] - njv[ja][r];
        f32x4 c = __builtin_amdgcn_mfma_f32_16x16x32_bf16(aj[ja], at[tb], cin, 0, 0, 0);
        #pragma unroll
        for (int r = 0; r < 4; r++) {
          const float p = __builtin_amdgcn_exp2f(c[r]);
          lsum[tb] += p;
          pfrag[tb][ja >> 1][(ja & 1) * 4 + r] = (short)f2bf(p);
        }
      }
    }
    __syncthreads();               // vmcnt drain + visibility: Bs tile ready
    // PV on Bs
    #pragma unroll
    for (int kb = 0; kb < 4; kb++) {
      short8 bfr[8];
      #pragma unroll
      for (int nb = 0; nb < 8; nb++)
        bfr[nb] = *(const short8*)&Bs[(nb * 16 + m) * 128 + (((kb * 4 + quad) ^ (m & 7)) * 8)];
      #pragma unroll
      for (int tb = 0; tb < 2; tb++)
        #pragma unroll
        for (int nb = 0; nb < 8; nb++)
          acc[tb][nb] = __builtin_amdgcn_mfma_f32_16x16x32_bf16(pfrag[tb][kb], bfr[nb], acc[tb][nb], 0, 0, 0);
    }
  }
  // row sums: butterfly over quads, publish via tiny LDS
  #pragma unroll
  for (int tb = 0; tb < 2; tb++) {
    lsum[tb] += __shfl_xor(lsum[tb], 16, 64);
    lsum[tb] += __shfl_xor(lsum[tb], 32, 64);
  }
  if (quad == 0) { l_s[w * 32 + m] = lsum[0]; l_s[w * 32 + 16 + m] = lsum[1]; }
  __syncthreads();
  // epilogue: out = acc / l   (C rows = quad*4+r, cols = m)
  #pragma unroll
  for (int tb = 0; tb < 2; tb++) {
    f32x4 lv = *(const f32x4*)&l_s[w * 32 + tb * 16 + quad * 4];
    f32x4 inv;
    #pragma unroll
    for (int r = 0; r < 4; r++) inv[r] = 1.f / lv[r];
    float* ob = out + ((size_t)bz * T_ + t0 + w * 32 + tb * 16 + quad * 4) * D_ + d0;
    #pragma unroll
    for (int nb = 0; nb < 8; nb++)
      #pragma unroll
      for (int r = 0; r < 4; r++)
        ob[(size_t)r * D_ + nb * 16 + m] = acc[tb][nb][r] * inv[r];
  }
#undef STAGE
}

extern "C" void kernel_launch(void* const* d_in, const int* in_sizes, int n_in,
                              void* d_out, int out_size, void* d_ws, size_t ws_size,
                              hipStream_t stream) {
  const float* x = (const float*)d_in[0];
  const float* U = (const float*)d_in[1];
  float* out = (float*)d_out;

  const size_t xt_b  = (size_t)B_ * D_ * T_ * 2;      // 16 MB
  const size_t ybf_b = (size_t)B_ * T_ * R_ * 2;      // 512 KB
  const size_t nsq_b = (size_t)B_ * T_ * 4;           // 32 KB
  const size_t yp_b  = (size_t)8 * B_ * R_ * T_ * 4;  // 8 MB partial y [slab][b][r][t]

  char* wp = (char*)d_ws;
  unsigned short* xtp = (unsigned short*)wp;                 wp += xt_b;
  unsigned short* ybf = (unsigned short*)wp;                 wp += ybf_b;
  float* nsq = (float*)wp;                                   wp += nsq_b;
  float* ypart = (float*)wp;                                 wp += yp_b;
  (void)ws_size; (void)in_sizes; (void)n_in; (void)out_size;

  hipLaunchKernelGGL(geo_prep, dim3(T_ / 128, B_, D_ / 128), dim3(256), 0, stream,
                     x, U, xtp, ypart);
  hipLaunchKernelGGL(geo_reduce, dim3(T_ / 128, B_), dim3(256), 0, stream,
                     ypart, ybf, nsq);
  hipLaunchKernelGGL(geo_fused, dim3((T_ / 128) * (D_ / 128), 1, B_), dim3(256), 0, stream,
                     ybf, nsq, xtp, out);
}

// Round 4
// 175.392 us; speedup vs baseline: 1.0054x; 1.0054x over previous
//
#include <hip/hip_runtime.h>

// GeodesicAttention: B=4, T=2048, D=1024, R=32
//   y = x @ U; p[t,j] = exp(2 y_t.y_j - n_j - n_t) in (0,1], NO online max.
// Round 10 = round 9's verified register-P math + round-1's load coverage:
//   - Bs double-buffered at 64-wide j-tiles: [2][128*64] = 32 KB (+l_s 512B
//     = 33,280 B total — the footprint proven to launch; round-2's 66 KB
//     static LDS silently failed).
//   - Per iter: prefetch aj(it+1) -> scores(it) [regs only] -> barrier
//     (drains STAGE(it); coverage = PV(it-1)+scores(it)) -> STAGE(it+1)
//     -> PV(it). One barrier/iter. Buffer races all barrier-separated.
//   - Static buf/register rotation via 2-body unroll (no runtime-indexed
//     register arrays -> no scratch).
//   - geo_reduce regridded 64 -> 256 blocks (was using 25% of CUs).
#define B_ 4
#define T_ 2048
#define D_ 1024
#define R_ 32
#define XP 136   // LDS pad stride in shorts for 128-wide bf16 tiles

typedef __attribute__((ext_vector_type(8))) short short8;
typedef __attribute__((ext_vector_type(4))) float f32x4;
typedef __attribute__((ext_vector_type(4))) unsigned short us4;
typedef __attribute__((ext_vector_type(8))) unsigned short us8;

__device__ __forceinline__ unsigned short f2bf(float f) {
  union { float f; unsigned u; } v; v.f = f;
  unsigned r = (v.u + 0x7fffu + ((v.u >> 16) & 1u)) >> 16;
  return (unsigned short)r;
}
__device__ __forceinline__ float bf2f(unsigned short h) {
  union { unsigned u; float f; } v; v.u = (unsigned)h << 16;
  return v.f;
}

// ---------------- prep: xt + Ut (in-LDS) + partial y ------------------------
// Block = 128 t x 128 d. grid (T/128, B, D/128). (unchanged, verified)
__global__ __launch_bounds__(256)
void geo_prep(const float* __restrict__ x, const float* __restrict__ U,
              unsigned short* __restrict__ xt, float* __restrict__ ypart) {
  __shared__ unsigned short xs[128 * XP];   // bf16 x tile [t][d]
  __shared__ unsigned short uts[32 * XP];   // bf16 U^T slab [r][d]
  const int bb = blockIdx.y, t0 = blockIdx.x * 128, d0 = blockIdx.z * 128;
  const int tid = threadIdx.x, w = tid >> 6, lane = tid & 63;
  const int m = lane & 15, quad = lane >> 4;

  f32x4 uv[4];
  #pragma unroll
  for (int p = 0; p < 4; p++) {
    const int i4 = p * 256 + tid;            // (du = i4>>3, ru4 = i4&7)
    uv[p] = *(const f32x4*)(U + (size_t)(d0 + (i4 >> 3)) * R_ + (i4 & 7) * 4);
  }
  f32x4 xv[16];
  #pragma unroll
  for (int p = 0; p < 16; p++) {
    const int i4 = p * 256 + tid;            // (r = i4>>5, c4 = i4&31)
    xv[p] = *(const f32x4*)(x + ((size_t)bb * T_ + t0 + (i4 >> 5)) * D_ + d0 + (i4 & 31) * 4);
  }
  #pragma unroll
  for (int p = 0; p < 4; p++) {
    const int i4 = p * 256 + tid; const int du = i4 >> 3, ru4 = i4 & 7;
    #pragma unroll
    for (int k = 0; k < 4; k++) uts[(ru4 * 4 + k) * XP + du] = f2bf(uv[p][k]);
  }
  #pragma unroll
  for (int p = 0; p < 16; p++) {
    const int i4 = p * 256 + tid; const int r = i4 >> 5, c4 = i4 & 31;
    us4 c;
    c[0] = f2bf(xv[p][0]); c[1] = f2bf(xv[p][1]);
    c[2] = f2bf(xv[p][2]); c[3] = f2bf(xv[p][3]);
    *(us4*)&xs[r * XP + c4 * 4] = c;
  }
  __syncthreads();
  {
    const int d = tid >> 1, th = tid & 1;
    unsigned short* xo = xt + ((size_t)bb * D_ + d0 + d) * T_ + t0 + th * 64;
    #pragma unroll
    for (int i = 0; i < 8; i++) {
      us8 o;
      #pragma unroll
      for (int k = 0; k < 8; k++) o[k] = xs[(th * 64 + i * 8 + k) * XP + d];
      *(us8*)(xo + i * 8) = o;
    }
  }
  f32x4 acc[2][2];
  #pragma unroll
  for (int i = 0; i < 2; i++)
    #pragma unroll
    for (int j = 0; j < 2; j++) acc[i][j] = (f32x4){0.f, 0.f, 0.f, 0.f};
  #pragma unroll
  for (int ks = 0; ks < 4; ks++) {
    const int ko = ks * 32 + quad * 8;
    short8 a0 = *(const short8*)&xs[(w * 32 + m) * XP + ko];
    short8 a1 = *(const short8*)&xs[(w * 32 + 16 + m) * XP + ko];
    short8 b0 = *(const short8*)&uts[m * XP + ko];
    short8 b1 = *(const short8*)&uts[(16 + m) * XP + ko];
    acc[0][0] = __builtin_amdgcn_mfma_f32_16x16x32_bf16(a0, b0, acc[0][0], 0, 0, 0);
    acc[0][1] = __builtin_amdgcn_mfma_f32_16x16x32_bf16(a0, b1, acc[0][1], 0, 0, 0);
    acc[1][0] = __builtin_amdgcn_mfma_f32_16x16x32_bf16(a1, b0, acc[1][0], 0, 0, 0);
    acc[1][1] = __builtin_amdgcn_mfma_f32_16x16x32_bf16(a1, b1, acc[1][1], 0, 0, 0);
  }
  #pragma unroll
  for (int tb = 0; tb < 2; tb++)
    #pragma unroll
    for (int nb = 0; nb < 2; nb++)
      *(f32x4*)(ypart + ((size_t)(blockIdx.z * B_ + bb) * R_ + nb * 16 + m) * T_
                + t0 + w * 32 + tb * 16 + quad * 4) = acc[tb][nb];
}

// ---------------- reduce: y = sum_s ypart; ybf (exp2-scaled), nsq -----------
// Block = 32 t. grid (T/32, B) = 256 blocks. SCALE = sqrt(2/ln2).
__global__ __launch_bounds__(256)
void geo_reduce(const float* __restrict__ ypart, unsigned short* __restrict__ ybf,
                float* __restrict__ nsq) {
  __shared__ float ls[32][36];   // [r][t], padded
  const int t0 = blockIdx.x * 32, bb = blockIdx.y;
  const int tid = threadIdx.x;
  {
    const int r = tid >> 3, t4 = (tid & 7) * 4;   // 1 r-row, 4 t per thread
    f32x4 v = {0.f, 0.f, 0.f, 0.f};
    #pragma unroll
    for (int s = 0; s < 8; s++) {
      f32x4 p = *(const f32x4*)(ypart + ((size_t)(s * B_ + bb) * R_ + r) * T_ + t0 + t4);
      #pragma unroll
      for (int k = 0; k < 4; k++) v[k] += p[k];
    }
    *(f32x4*)&ls[r][t4] = v;
  }
  __syncthreads();
  const int t = tid >> 3, r4 = (tid & 7) * 4;     // 1 t-row, 4 r per thread
  us4 pk; float part = 0.f;
  #pragma unroll
  for (int k = 0; k < 4; k++) {
    const unsigned short h = f2bf(1.69864446f * ls[r4 + k][t]);
    const float bv = bf2f(h); part += bv * bv; pk[k] = h;
  }
  *(us4*)(ybf + ((size_t)bb * T_ + t0 + t) * R_ + r4) = pk;
  part += __shfl_xor(part, 1, 64);
  part += __shfl_xor(part, 2, 64);
  part += __shfl_xor(part, 4, 64);
  if ((tid & 7) == 0) nsq[bb * T_ + t0 + t] = 0.5f * part;
}

// ---------------- fused: out[t, d-slab] = (exp2-P @ xt^T) / rowsum ----------
// Block = (t-tile 128) x (d-slab 128); wave w owns out rows [w*32, w*32+32).
// 64-wide j-tiles, dbuf LDS, cross-iteration load coverage, P in registers.
__global__ __launch_bounds__(256, 2)
void geo_fused(const unsigned short* __restrict__ ybf,
               const float* __restrict__ nsq,
               const unsigned short* __restrict__ xt,
               float* __restrict__ out) {
  __shared__ unsigned short Bs[2][128 * 64];   // xt tiles, XOR-swizzled (32 KB)
  __shared__ float l_s[128];
  const int bz = blockIdx.z, id = blockIdx.x;
  const int d0 = (id & 7) * 128;   // id%8 -> d-slab: each XCD reuses one xt panel
  const int t0 = (id >> 3) * 128;
  const int tid = threadIdx.x, w = tid >> 6, lane = tid & 63;
  const int m = lane & 15, quad = lane >> 4;
  const int srow = lane >> 3, sslot = lane & 7;

  const unsigned short* yb = ybf + (size_t)bz * T_ * R_;
  const float* nq = nsq + bz * T_;
  const unsigned short* Xb = xt + ((size_t)bz * D_ + d0) * T_;

// stage 128 d-rows x 64 j into Bs[BUF]; 4 instrs/wave, 8 rows each, linear
// LDS dest (lane = srow*8+sslot -> row-major), pre-swizzled global source.
#define STAGE(J0, BUF) do {                                                      \
    _Pragma("unroll")                                                            \
    for (int cc = 0; cc < 4; cc++) {                                             \
      const int rbase = w * 32 + cc * 8;                                         \
      const int row = rbase + srow;                                              \
      const int sw = (sslot ^ (row & 7)) * 8;                                    \
      __builtin_amdgcn_global_load_lds(                                          \
        (const __attribute__((address_space(1))) void*)(Xb + (size_t)row * T_ + (J0) + sw), \
        (__attribute__((address_space(3))) void*)(&Bs[BUF][rbase * 64]), 16, 0, 0); \
    } } while (0)

// one 64-j iteration: prefetch aj(IT+1) into AJN/NJN, scores from AJC/NJC,
// barrier (drains STAGE(IT)), STAGE(IT+1 -> BUFN), PV on Bs[BUFC].
#define BODY(IT, AJC, NJC, AJN, NJN, BUFC, BUFN) do {                            \
    const int j0b = (IT) * 64;                                                   \
    const int jn0 = (((IT) + 1) & 31) * 64;                                      \
    _Pragma("unroll")                                                            \
    for (int ja = 0; ja < 4; ja++) {                                             \
      const int jr = 32 * (ja >> 1) + 8 * (m >> 2) + (ja & 1) * 4 + (m & 3);     \
      AJN[ja] = *(const short8*)(yb + (size_t)(jn0 + jr) * R_ + quad * 8);       \
      NJN[ja] = *(const f32x4*)(nq + jn0 + 32 * (ja >> 1) + (ja & 1) * 4 + 8 * quad); \
    }                                                                            \
    short8 pfrag[2][2];                                                          \
    _Pragma("unroll")                                                            \
    for (int tb = 0; tb < 2; tb++) {                                             \
      _Pragma("unroll")                                                          \
      for (int ja = 0; ja < 4; ja++) {                                           \
        f32x4 cin;                                                               \
        _Pragma("unroll")                                                        \
        for (int r = 0; r < 4; r++) cin[r] = nnt[tb] - NJC[ja][r];               \
        f32x4 c = __builtin_amdgcn_mfma_f32_16x16x32_bf16(AJC[ja], at[tb], cin, 0, 0, 0); \
        _Pragma("unroll")                                                        \
        for (int r = 0; r < 4; r++) {                                            \
          const float p = __builtin_amdgcn_exp2f(c[r]);                          \
          lsum4[tb][r] += p;                                                     \
          pfrag[tb][ja >> 1][(ja & 1) * 4 + r] = (short)f2bf(p);                 \
        }                                                                        \
      }                                                                          \
    }                                                                            \
    __syncthreads();                  /* drains STAGE(IT): cover = PV+scores */  \
    if ((IT) + 1 < 32) STAGE(j0b + 64, BUFN);                                    \
    _Pragma("unroll")                                                            \
    for (int kb = 0; kb < 2; kb++) {                                             \
      short8 bfr[8];                                                             \
      _Pragma("unroll")                                                          \
      for (int nb = 0; nb < 8; nb++)                                             \
        bfr[nb] = *(const short8*)&Bs[BUFC][(nb * 16 + m) * 64 + (((kb * 4 + quad) ^ (m & 7)) * 8)]; \
      _Pragma("unroll")                                                          \
      for (int tb = 0; tb < 2; tb++)                                             \
        _Pragma("unroll")                                                        \
        for (int nb = 0; nb < 8; nb++)                                           \
          acc[tb][nb] = __builtin_amdgcn_mfma_f32_16x16x32_bf16(pfrag[tb][kb], bfr[nb], acc[tb][nb], 0, 0, 0); \
    } } while (0)

  // hoisted t-side fragments
  short8 at[2]; float nnt[2]; f32x4 lsum4[2];
  #pragma unroll
  for (int tb = 0; tb < 2; tb++) {
    at[tb] = *(const short8*)(yb + (size_t)(t0 + w * 32 + tb * 16 + m) * R_ + quad * 8);
    nnt[tb] = -nq[t0 + w * 32 + tb * 16 + m];
    lsum4[tb] = (f32x4){0.f, 0.f, 0.f, 0.f};
  }

  f32x4 acc[2][8];
  #pragma unroll
  for (int i = 0; i < 2; i++)
    #pragma unroll
    for (int j = 0; j < 8; j++) acc[i][j] = (f32x4){0.f, 0.f, 0.f, 0.f};

  // prologue: j-tile 0 fragments + stage tile 0
  short8 ajA[4], ajB[4]; f32x4 njA[4], njB[4];
  #pragma unroll
  for (int ja = 0; ja < 4; ja++) {
    const int jr = 32 * (ja >> 1) + 8 * (m >> 2) + (ja & 1) * 4 + (m & 3);
    ajA[ja] = *(const short8*)(yb + (size_t)jr * R_ + quad * 8);
    njA[ja] = *(const f32x4*)(nq + 32 * (ja >> 1) + (ja & 1) * 4 + 8 * quad);
  }
  STAGE(0, 0);

  for (int it2 = 0; it2 < 16; it2++) {
    const int it0 = it2 * 2;
    BODY(it0,     ajA, njA, ajB, njB, 0, 1);
    BODY(it0 + 1, ajB, njB, ajA, njA, 1, 0);
  }

  // row sums: sum vector partials, butterfly over quads, publish via LDS
  float lsum[2];
  #pragma unroll
  for (int tb = 0; tb < 2; tb++) {
    lsum[tb] = lsum4[tb][0] + lsum4[tb][1] + lsum4[tb][2] + lsum4[tb][3];
    lsum[tb] += __shfl_xor(lsum[tb], 16, 64);
    lsum[tb] += __shfl_xor(lsum[tb], 32, 64);
  }
  if (quad == 0) { l_s[w * 32 + m] = lsum[0]; l_s[w * 32 + 16 + m] = lsum[1]; }
  __syncthreads();
  // epilogue: out = acc / l   (C rows = quad*4+r, cols = m)
  #pragma unroll
  for (int tb = 0; tb < 2; tb++) {
    f32x4 lv = *(const f32x4*)&l_s[w * 32 + tb * 16 + quad * 4];
    f32x4 inv;
    #pragma unroll
    for (int r = 0; r < 4; r++) inv[r] = 1.f / lv[r];
    float* ob = out + ((size_t)bz * T_ + t0 + w * 32 + tb * 16 + quad * 4) * D_ + d0;
    #pragma unroll
    for (int nb = 0; nb < 8; nb++)
      #pragma unroll
      for (int r = 0; r < 4; r++)
        ob[(size_t)r * D_ + nb * 16 + m] = acc[tb][nb][r] * inv[r];
  }
#undef BODY
#undef STAGE
}

extern "C" void kernel_launch(void* const* d_in, const int* in_sizes, int n_in,
                              void* d_out, int out_size, void* d_ws, size_t ws_size,
                              hipStream_t stream) {
  const float* x = (const float*)d_in[0];
  const float* U = (const float*)d_in[1];
  float* out = (float*)d_out;

  const size_t xt_b  = (size_t)B_ * D_ * T_ * 2;      // 16 MB
  const size_t ybf_b = (size_t)B_ * T_ * R_ * 2;      // 512 KB
  const size_t nsq_b = (size_t)B_ * T_ * 4;           // 32 KB
  const size_t yp_b  = (size_t)8 * B_ * R_ * T_ * 4;  // 8 MB partial y [slab][b][r][t]

  char* wp = (char*)d_ws;
  unsigned short* xtp = (unsigned short*)wp;                 wp += xt_b;
  unsigned short* ybf = (unsigned short*)wp;                 wp += ybf_b;
  float* nsq = (float*)wp;                                   wp += nsq_b;
  float* ypart = (float*)wp;                                 wp += yp_b;
  (void)ws_size; (void)in_sizes; (void)n_in; (void)out_size;

  hipLaunchKernelGGL(geo_prep, dim3(T_ / 128, B_, D_ / 128), dim3(256), 0, stream,
                     x, U, xtp, ypart);
  hipLaunchKernelGGL(geo_reduce, dim3(T_ / 32, B_), dim3(256), 0, stream,
                     ypart, ybf, nsq);
  hipLaunchKernelGGL(geo_fused, dim3((T_ / 128) * (D_ / 128), 1, B_), dim3(256), 0, stream,
                     ybf, nsq, xtp, out);
}

// Round 6
// 158.666 us; speedup vs baseline: 1.1114x; 1.1054x over previous
//
#include <hip/hip_runtime.h>
#include <hip/hip_bf16.h>

// GeodesicAttention: B=4, T=2048, D=1024, R=32
//   y = x @ U; p[t,j] = exp(2 y_t.y_j - n_j - n_t) in (0,1], NO online max.
// Round 12 = round 11 with the prep transpose unswizzle fixed:
//   xs stores row r, logical granule g at physical g ^ (r&7). The 8x8-subtile
//   transpose reads rows t = ts*8+k, so the unswizzle is dsb ^ k (row&7 == k),
//   NOT dsb ^ (ts&7). One-expression fix; everything else identical.
//   - fused: t-tile 64 (grid 1024 = 4 blocks/CU), P in registers via the
//     permuted-fragment score MFMA, cvt_pk bf16 packing.
//   - prep: 8x8 register transpose, 4x256B coalesced xt stores per instr.
#define B_ 4
#define T_ 2048
#define D_ 1024
#define R_ 32
#define XP 136   // LDS row stride in shorts (272B = 17*16B)

typedef __attribute__((ext_vector_type(8))) short short8;
typedef __attribute__((ext_vector_type(4))) float f32x4;
typedef __attribute__((ext_vector_type(4))) unsigned short us4;
typedef __attribute__((ext_vector_type(8))) unsigned short us8;

__device__ __forceinline__ unsigned short f2bf(float f) {
  union { float f; unsigned u; } v; v.f = f;
  unsigned r = (v.u + 0x7fffu + ((v.u >> 16) & 1u)) >> 16;
  return (unsigned short)r;
}
__device__ __forceinline__ float bf2f(unsigned short h) {
  union { unsigned u; float f; } v; v.u = (unsigned)h << 16;
  return v.f;
}
__device__ __forceinline__ unsigned pk2bf(float a, float b) {
  union { __hip_bfloat162 h; unsigned u; } v;
  v.h = __float22bfloat162_rn(make_float2(a, b));   // v_cvt_pk_bf16_f32 (RNE)
  return v.u;
}

// ---------------- prep: xt + Ut (in-LDS) + partial y ------------------------
// Block = 128 t x 128 d. grid (T/128, B, D/128).
// xs layout: row t, d-granule g=(d>>3) stored at (g ^ (t&7)) — 16B granules.
__global__ __launch_bounds__(256)
void geo_prep(const float* __restrict__ x, const float* __restrict__ U,
              unsigned short* __restrict__ xt, float* __restrict__ ypart) {
  __shared__ unsigned short xs[128 * XP];   // bf16 x tile [t][d], granule-XOR
  __shared__ unsigned short uts[32 * XP];   // bf16 U^T slab [r][d]
  const int bb = blockIdx.y, t0 = blockIdx.x * 128, d0 = blockIdx.z * 128;
  const int tid = threadIdx.x, w = tid >> 6, lane = tid & 63;
  const int m = lane & 15, quad = lane >> 4;

  f32x4 uv[4];
  #pragma unroll
  for (int p = 0; p < 4; p++) {
    const int i4 = p * 256 + tid;            // (du = i4>>3, ru4 = i4&7)
    uv[p] = *(const f32x4*)(U + (size_t)(d0 + (i4 >> 3)) * R_ + (i4 & 7) * 4);
  }
  f32x4 xv[16];
  #pragma unroll
  for (int p = 0; p < 16; p++) {
    const int i4 = p * 256 + tid;            // (r = i4>>5, c4 = i4&31)
    xv[p] = *(const f32x4*)(x + ((size_t)bb * T_ + t0 + (i4 >> 5)) * D_ + d0 + (i4 & 31) * 4);
  }
  #pragma unroll
  for (int p = 0; p < 4; p++) {
    const int i4 = p * 256 + tid; const int du = i4 >> 3, ru4 = i4 & 7;
    #pragma unroll
    for (int k = 0; k < 4; k++) uts[(ru4 * 4 + k) * XP + du] = f2bf(uv[p][k]);
  }
  #pragma unroll
  for (int p = 0; p < 16; p++) {
    const int i4 = p * 256 + tid; const int r = i4 >> 5, c4 = i4 & 31;
    union { us4 c; unsigned u[2]; } cc;
    cc.u[0] = pk2bf(xv[p][0], xv[p][1]);
    cc.u[1] = pk2bf(xv[p][2], xv[p][3]);
    // granule g = c4>>1 (16B), physical granule = g ^ (r&7)
    *(us4*)&xs[r * XP + ((c4 >> 1) ^ (r & 7)) * 8 + (c4 & 1) * 4] = cc.c;
  }
  __syncthreads();
  // xt transposed store: thread = 8x8 subtile (ts = t-block, dsb = d-block).
  // Rows t = ts*8+k, so physical granule = dsb ^ ((ts*8+k)&7) = dsb ^ k.
  {
    const int ts = tid & 15, dsb = tid >> 4;
    us8 rowv[8];
    #pragma unroll
    for (int k = 0; k < 8; k++)
      rowv[k] = *(const us8*)&xs[(ts * 8 + k) * XP + ((dsb ^ k) * 8)];
    unsigned short* xo = xt + ((size_t)bb * D_ + d0 + dsb * 8) * T_ + t0 + ts * 8;
    #pragma unroll
    for (int dd = 0; dd < 8; dd++) {
      us8 o;
      #pragma unroll
      for (int k = 0; k < 8; k++) o[k] = rowv[k][dd];
      *(us8*)(xo + (size_t)dd * T_) = o;
    }
  }
  // partial y: A = x rows (t, 32/wave), B = uts rows (r), K = 128
  f32x4 acc[2][2];
  #pragma unroll
  for (int i = 0; i < 2; i++)
    #pragma unroll
    for (int j = 0; j < 2; j++) acc[i][j] = (f32x4){0.f, 0.f, 0.f, 0.f};
  #pragma unroll
  for (int ks = 0; ks < 4; ks++) {
    const int ko = ks * 32 + quad * 8;
    const int go = ((ks * 4 + quad) ^ (m & 7)) * 8;   // swizzled granule offset
    short8 a0 = *(const short8*)&xs[(w * 32 + m) * XP + go];
    short8 a1 = *(const short8*)&xs[(w * 32 + 16 + m) * XP + go];
    short8 b0 = *(const short8*)&uts[m * XP + ko];
    short8 b1 = *(const short8*)&uts[(16 + m) * XP + ko];
    acc[0][0] = __builtin_amdgcn_mfma_f32_16x16x32_bf16(a0, b0, acc[0][0], 0, 0, 0);
    acc[0][1] = __builtin_amdgcn_mfma_f32_16x16x32_bf16(a0, b1, acc[0][1], 0, 0, 0);
    acc[1][0] = __builtin_amdgcn_mfma_f32_16x16x32_bf16(a1, b0, acc[1][0], 0, 0, 0);
    acc[1][1] = __builtin_amdgcn_mfma_f32_16x16x32_bf16(a1, b1, acc[1][1], 0, 0, 0);
  }
  #pragma unroll
  for (int tb = 0; tb < 2; tb++)
    #pragma unroll
    for (int nb = 0; nb < 2; nb++)
      *(f32x4*)(ypart + ((size_t)(blockIdx.z * B_ + bb) * R_ + nb * 16 + m) * T_
                + t0 + w * 32 + tb * 16 + quad * 4) = acc[tb][nb];
}

// ---------------- reduce: y = sum_s ypart; ybf (exp2-scaled), nsq -----------
// Block = 32 t. grid (T/32, B). SCALE = sqrt(2/ln2).
__global__ __launch_bounds__(256)
void geo_reduce(const float* __restrict__ ypart, unsigned short* __restrict__ ybf,
                float* __restrict__ nsq) {
  __shared__ float ls[32][36];   // [r][t], padded
  const int t0 = blockIdx.x * 32, bb = blockIdx.y;
  const int tid = threadIdx.x;
  {
    const int r = tid >> 3, t4 = (tid & 7) * 4;
    f32x4 v = {0.f, 0.f, 0.f, 0.f};
    #pragma unroll
    for (int s = 0; s < 8; s++) {
      f32x4 p = *(const f32x4*)(ypart + ((size_t)(s * B_ + bb) * R_ + r) * T_ + t0 + t4);
      #pragma unroll
      for (int k = 0; k < 4; k++) v[k] += p[k];
    }
    *(f32x4*)&ls[r][t4] = v;
  }
  __syncthreads();
  const int t = tid >> 3, r4 = (tid & 7) * 4;
  us4 pk; float part = 0.f;
  #pragma unroll
  for (int k = 0; k < 4; k++) {
    const unsigned short h = f2bf(1.69864446f * ls[r4 + k][t]);
    const float bv = bf2f(h); part += bv * bv; pk[k] = h;
  }
  *(us4*)(ybf + ((size_t)bb * T_ + t0 + t) * R_ + r4) = pk;
  part += __shfl_xor(part, 1, 64);
  part += __shfl_xor(part, 2, 64);
  part += __shfl_xor(part, 4, 64);
  if ((tid & 7) == 0) nsq[bb * T_ + t0 + t] = 0.5f * part;
}

// ---------------- fused: out[t, d-slab] = (exp2-P @ xt^T) / rowsum ----------
// Block = (t-tile 64) x (d-slab 128); wave w owns out rows [w*16, w*16+16).
// grid (T/64)*(D/128) x B = 1024 blocks = 4 blocks/CU. P stays in registers.
__global__ __launch_bounds__(256, 4)
void geo_fused(const unsigned short* __restrict__ ybf,
               const float* __restrict__ nsq,
               const unsigned short* __restrict__ xt,
               float* __restrict__ out) {
  __shared__ unsigned short Bs[2][128 * 64];   // xt tiles, XOR-swizzled (32 KB)
  __shared__ float l_s[64];
  const int bz = blockIdx.z, id = blockIdx.x;
  const int d0 = (id & 7) * 128;   // id%8 -> d-slab: each XCD reuses one xt panel
  const int t0 = (id >> 3) * 64;
  const int tid = threadIdx.x, w = tid >> 6, lane = tid & 63;
  const int m = lane & 15, quad = lane >> 4;
  const int srow = lane >> 3, sslot = lane & 7;
  const int tw = w * 16;

  const unsigned short* yb = ybf + (size_t)bz * T_ * R_;
  const float* nq = nsq + bz * T_;
  const unsigned short* Xb = xt + ((size_t)bz * D_ + d0) * T_;

// stage 128 d-rows x 64 j into Bs[BUF]; 4 instrs/wave, linear LDS dest,
// pre-swizzled global source.
#define STAGE(J0, BUF) do {                                                      \
    _Pragma("unroll")                                                            \
    for (int cc = 0; cc < 4; cc++) {                                             \
      const int rbase = w * 32 + cc * 8;                                         \
      const int row = rbase + srow;                                              \
      const int sw = (sslot ^ (row & 7)) * 8;                                    \
      __builtin_amdgcn_global_load_lds(                                          \
        (const __attribute__((address_space(1))) void*)(Xb + (size_t)row * T_ + (J0) + sw), \
        (__attribute__((address_space(3))) void*)(&Bs[BUF][rbase * 64]), 16, 0, 0); \
    } } while (0)

  // hoisted t-side fragment (16 rows per wave)
  short8 at = *(const short8*)(yb + (size_t)(t0 + tw + m) * R_ + quad * 8);
  const float nnt = -nq[t0 + tw + m];
  f32x4 lsum4 = {0.f, 0.f, 0.f, 0.f};

  f32x4 acc[8];
  #pragma unroll
  for (int j = 0; j < 8; j++) acc[j] = (f32x4){0.f, 0.f, 0.f, 0.f};

  STAGE(0, 0);   // prologue: tile 0 -> Bs[0]

  for (int it = 0; it < 32; ++it) {
    const int j0 = it * 64, buf = it & 1;
    // j-side fragments, PERMUTED rows: frag-row i <- global j = g(ja,i)
    short8 aj[4]; f32x4 njv[4];
    #pragma unroll
    for (int ja = 0; ja < 4; ja++) {
      const int jr = 32 * (ja >> 1) + 8 * (m >> 2) + (ja & 1) * 4 + (m & 3);
      aj[ja] = *(const short8*)(yb + (size_t)(j0 + jr) * R_ + quad * 8);
      njv[ja] = *(const f32x4*)(nq + j0 + 32 * (ja >> 1) + (ja & 1) * 4 + 8 * quad);
    }
    // scores -> exp2 -> bf16 PV A-frags, fully in registers
    union { short8 s; unsigned u[4]; } pf[2];
    #pragma unroll
    for (int ja = 0; ja < 4; ja++) {
      f32x4 cin;
      #pragma unroll
      for (int r = 0; r < 4; r++) cin[r] = nnt - njv[ja][r];
      f32x4 c = __builtin_amdgcn_mfma_f32_16x16x32_bf16(aj[ja], at, cin, 0, 0, 0);
      f32x4 p;
      #pragma unroll
      for (int r = 0; r < 4; r++) {
        p[r] = __builtin_amdgcn_exp2f(c[r]);
        lsum4[r] += p[r];
      }
      pf[ja >> 1].u[(ja & 1) * 2 + 0] = pk2bf(p[0], p[1]);
      pf[ja >> 1].u[(ja & 1) * 2 + 1] = pk2bf(p[2], p[3]);
    }
    __syncthreads();                 // drains STAGE(it); coverage = PV(it-1)+scores(it)
    if (it + 1 < 32) STAGE(j0 + 64, buf ^ 1);
    // PV on Bs[buf]
    #pragma unroll
    for (int kb = 0; kb < 2; kb++) {
      short8 bfr[8];
      #pragma unroll
      for (int nb = 0; nb < 8; nb++)
        bfr[nb] = *(const short8*)&Bs[buf][(nb * 16 + m) * 64 + (((kb * 4 + quad) ^ (m & 7)) * 8)];
      #pragma unroll
      for (int nb = 0; nb < 8; nb++)
        acc[nb] = __builtin_amdgcn_mfma_f32_16x16x32_bf16(pf[kb].s, bfr[nb], acc[nb], 0, 0, 0);
    }
  }
  // row sums: butterfly over quads, publish via tiny LDS
  float lsum = lsum4[0] + lsum4[1] + lsum4[2] + lsum4[3];
  lsum += __shfl_xor(lsum, 16, 64);
  lsum += __shfl_xor(lsum, 32, 64);
  if (quad == 0) l_s[tw + m] = lsum;
  __syncthreads();
  // epilogue: out = acc / l   (C rows = quad*4+r, cols = m)
  {
    f32x4 lv = *(const f32x4*)&l_s[tw + quad * 4];
    f32x4 inv;
    #pragma unroll
    for (int r = 0; r < 4; r++) inv[r] = 1.f / lv[r];
    float* ob = out + ((size_t)bz * T_ + t0 + tw + quad * 4) * D_ + d0;
    #pragma unroll
    for (int nb = 0; nb < 8; nb++)
      #pragma unroll
      for (int r = 0; r < 4; r++)
        ob[(size_t)r * D_ + nb * 16 + m] = acc[nb][r] * inv[r];
  }
#undef STAGE
}

extern "C" void kernel_launch(void* const* d_in, const int* in_sizes, int n_in,
                              void* d_out, int out_size, void* d_ws, size_t ws_size,
                              hipStream_t stream) {
  const float* x = (const float*)d_in[0];
  const float* U = (const float*)d_in[1];
  float* out = (float*)d_out;

  const size_t xt_b  = (size_t)B_ * D_ * T_ * 2;      // 16 MB
  const size_t ybf_b = (size_t)B_ * T_ * R_ * 2;      // 512 KB
  const size_t nsq_b = (size_t)B_ * T_ * 4;           // 32 KB
  const size_t yp_b  = (size_t)8 * B_ * R_ * T_ * 4;  // 8 MB partial y [slab][b][r][t]

  char* wp = (char*)d_ws;
  unsigned short* xtp = (unsigned short*)wp;                 wp += xt_b;
  unsigned short* ybf = (unsigned short*)wp;                 wp += ybf_b;
  float* nsq = (float*)wp;                                   wp += nsq_b;
  float* ypart = (float*)wp;                                 wp += yp_b;
  (void)ws_size; (void)in_sizes; (void)n_in; (void)out_size;

  hipLaunchKernelGGL(geo_prep, dim3(T_ / 128, B_, D_ / 128), dim3(256), 0, stream,
                     x, U, xtp, ypart);
  hipLaunchKernelGGL(geo_reduce, dim3(T_ / 32, B_), dim3(256), 0, stream,
                     ypart, ybf, nsq);
  hipLaunchKernelGGL(geo_fused, dim3((T_ / 64) * (D_ / 128), 1, B_), dim3(256), 0, stream,
                     ybf, nsq, xtp, out);
}